// Round 1
// 306.337 us; speedup vs baseline: 1.0040x; 1.0040x over previous
//
#include <hip/hip_runtime.h>
#include <math.h>

#define HH 256
#define WW 256
#define BC 512   // B*C = 8*64
#define QN 100

// ---------------------------------------------------------------------------
// Kernel 1: per-(b,c) 18x100 GEMM + q output + derived conv coefficients.
// coef layout per bc (stride 32 floats): [0..8]=former, [9..17]=wk,
// [18..26]=|wk|, [27..29]=column sums of wk (kept for layout compat).
// ---------------------------------------------------------------------------
__global__ __launch_bounds__(128) void prep_kernel(
    const float* __restrict__ query,   // (100, 8, 64) = (100, 512)
    const float* __restrict__ Wl,      // (18, 100)
    const float* __restrict__ bl,      // (18,)
    const float* __restrict__ Wd,      // (100, 18)
    const float* __restrict__ bd,      // (100,)
    float* __restrict__ qout,          // (100, 512) region of d_out
    float* __restrict__ coef)          // (512, 32) in d_ws
{
    const int bc = blockIdx.x;
    const int t  = threadIdx.x;
    __shared__ float qcol[QN];
    __shared__ float c18[18];

    if (t < QN) qcol[t] = query[t * BC + bc];
    __syncthreads();

    if (t < 18) {
        float acc = bl[t];
        const float* wrow = Wl + t * QN;
        #pragma unroll 4
        for (int qi = 0; qi < QN; ++qi) acc += qcol[qi] * wrow[qi];
        c18[t] = acc;
    }
    __syncthreads();

    if (t < QN) {
        float acc = bd[t];
        const float* wrow = Wd + t * 18;
        #pragma unroll
        for (int k = 0; k < 18; ++k) acc += c18[k] * wrow[k];
        qout[t * BC + bc] = acc;   // q.transpose(2,0,1) layout
    }

    if (t < 18) {
        coef[bc * 32 + t] = c18[t];                      // former / wk
    } else if (t < 27) {
        coef[bc * 32 + t] = fabsf(c18[t - 9]);           // |wk|
    } else if (t < 30) {
        int j = t - 27;
        coef[bc * 32 + t] = c18[9 + j] + c18[12 + j] + c18[15 + j]; // colsum
    }
}

// ---------------------------------------------------------------------------
// Kernel 2: fused depthwise pipeline, 64x64 tile per block, 256 threads.
// Vectorized 4 columns per lane: all hot LDS traffic is aligned ds_read_b128 /
// ds_write_b128 (row stride 68 floats = 272 B = 17*16 B, 16B-aligned; 68%32=4
// gives uniform bank spread across the wave's 4 row-groups).
//   sval[r][c]  = value(h0-2+r, w0-2+c)   r<68, c<68  (zero outside image)
//   sdiff[r][c] = diff (h0-1+r, w0-1+c)   r<66, c<66  (zero outside image;
//                 cols 66,67 of sdiff are never written and never consumed)
// Lane layout: grp = lane>>4 (row-group), x4 = (lane&15)*4 (column base).
// Stream s = wave*4+grp owns 4 consecutive rows.
// Algebraic fold: res - res_diff = sum_b wk[b]*(vd0-vd1) + wk[6+b]*(vd2-vd1)
// (middle row cancels because ws[b] = wk[b]+wk[3+b]+wk[6+b]).
// ---------------------------------------------------------------------------
__global__ __launch_bounds__(256, 4) void fused_kernel(
    const float* __restrict__ value,   // (512, 256, 256)
    const float* __restrict__ coef,    // (512, 32)
    float* __restrict__ yout)          // (512, 256, 256) region of d_out
{
    const int bc  = blockIdx.z;
    const int h0  = blockIdx.y * 64;
    const int w0  = blockIdx.x * 64;
    const int tid = threadIdx.x;
    const int wave = tid >> 6;
    const int lane = tid & 63;
    const int grp  = lane >> 4;        // 0..3 row-group within wave
    const int x4   = (lane & 15) << 2; // column base 0..60

    __shared__ __align__(16) float sval[68][68];
    __shared__ __align__(16) float sdiff[66][68];

    // coefficients: block-uniform address -> scalar (SGPR) loads
    const float* cp = coef + bc * 32;
    float fco[9], wk[9], awk[9];
    #pragma unroll
    for (int i = 0; i < 9; ++i) { fco[i] = cp[i]; wk[i] = cp[9 + i]; awk[i] = cp[18 + i]; }

    const float* vp = value + (size_t)bc * (HH * WW);

    // ---- phase 1: stage value 68x68 (origin h0-2, w0-2), float2 chunks ----
    #pragma unroll
    for (int it = 0; it < 10; ++it) {
        int idx = tid + it * 256;
        if (idx < 68 * 34) {
            int r = idx / 34;
            int m = idx - r * 34;
            int h = h0 - 2 + r;
            int w = w0 - 2 + 2 * m;
            float2 v = make_float2(0.f, 0.f);
            if ((unsigned)h < HH) {
                const float* rowp = vp + h * WW;
                if ((unsigned)w < WW)       v.x = rowp[w];
                if ((unsigned)(w + 1) < WW) v.y = rowp[w + 1];
            }
            *(float2*)&sval[r][2 * m] = v;
        }
    }
    __syncthreads();

    // ---- phase 2 main: sdiff rows 0..63, cols 0..63; 4 cols/lane, rolling
    //      3-row window of 8-wide register rows (2 x ds_read_b128 per row) ----
    {
        const int r0 = (wave * 4 + grp) * 4;   // rows r0..r0+3
        float cm[4];
        #pragma unroll
        for (int co = 0; co < 4; ++co)
            cm[co] = ((unsigned)(w0 - 1 + x4 + co) < WW) ? 1.f : 0.f;

        float a0[8], a1[8], a2[8];
        *(float4*)&a0[0] = *(const float4*)&sval[r0][x4];
        *(float4*)&a0[4] = *(const float4*)&sval[r0][x4 + 4];
        *(float4*)&a1[0] = *(const float4*)&sval[r0 + 1][x4];
        *(float4*)&a1[4] = *(const float4*)&sval[r0 + 1][x4 + 4];
        #pragma unroll
        for (int i = 0; i < 4; ++i) {
            const int r = r0 + i;
            *(float4*)&a2[0] = *(const float4*)&sval[r + 2][x4];
            *(float4*)&a2[4] = *(const float4*)&sval[r + 2][x4 + 4];
            const float rm = ((unsigned)(h0 - 1 + r) < HH) ? 1.f : 0.f;
            float4 od;
            #pragma unroll
            for (int co = 0; co < 4; ++co) {
                float yt = fco[0]*a0[co] + fco[1]*a0[co+1] + fco[2]*a0[co+2]
                         + fco[3]*a1[co] + fco[4]*a1[co+1] + fco[5]*a1[co+2]
                         + fco[6]*a2[co] + fco[7]*a2[co+1] + fco[8]*a2[co+2];
                float e = a1[co + 1] - yt;
                (&od.x)[co] = __expf(-e * e) * (rm * cm[co]);
            }
            *(float4*)&sdiff[r][x4] = od;
            #pragma unroll
            for (int j = 0; j < 8; ++j) { a0[j] = a1[j]; a1[j] = a2[j]; }
        }
    }

    // ---- phase 2 edge A: cols 64,65 for rows 0..65 (waves 0,1) ----
    if (tid < 66) {
        const int r = tid;
        float a0[4], a1[4], a2[4];
        *(float4*)a0 = *(const float4*)&sval[r][64];
        *(float4*)a1 = *(const float4*)&sval[r + 1][64];
        *(float4*)a2 = *(const float4*)&sval[r + 2][64];
        const float rm  = ((unsigned)(h0 - 1 + r) < HH) ? 1.f : 0.f;
        const float c65 = (w0 + 64 < WW) ? 1.f : 0.f;   // col 65 -> w = w0+64
        float2 od;
        {
            float yt = fco[0]*a0[0] + fco[1]*a0[1] + fco[2]*a0[2]
                     + fco[3]*a1[0] + fco[4]*a1[1] + fco[5]*a1[2]
                     + fco[6]*a2[0] + fco[7]*a2[1] + fco[8]*a2[2];
            float e = a1[1] - yt;
            od.x = __expf(-e * e) * rm;                  // col 64 always in-image
        }
        {
            float yt = fco[0]*a0[1] + fco[1]*a0[2] + fco[2]*a0[3]
                     + fco[3]*a1[1] + fco[4]*a1[2] + fco[5]*a1[3]
                     + fco[6]*a2[1] + fco[7]*a2[2] + fco[8]*a2[3];
            float e = a1[2] - yt;
            od.y = __expf(-e * e) * (rm * c65);
        }
        *(float2*)&sdiff[r][64] = od;
    }

    // ---- phase 2 edge B: rows 64,65, cols 0..63 (wave 2) ----
    if ((unsigned)(tid - 128) < 32u) {
        const int u  = tid - 128;
        const int r  = 64 + (u >> 4);
        const int c0 = (u & 15) << 2;
        float a0[8], a1[8], a2[8];
        *(float4*)&a0[0] = *(const float4*)&sval[r][c0];
        *(float4*)&a0[4] = *(const float4*)&sval[r][c0 + 4];
        *(float4*)&a1[0] = *(const float4*)&sval[r + 1][c0];
        *(float4*)&a1[4] = *(const float4*)&sval[r + 1][c0 + 4];
        *(float4*)&a2[0] = *(const float4*)&sval[r + 2][c0];
        *(float4*)&a2[4] = *(const float4*)&sval[r + 2][c0 + 4];
        const float rm = ((unsigned)(h0 - 1 + r) < HH) ? 1.f : 0.f;
        float4 od;
        #pragma unroll
        for (int co = 0; co < 4; ++co) {
            const float cmv = ((unsigned)(w0 - 1 + c0 + co) < WW) ? 1.f : 0.f;
            float yt = fco[0]*a0[co] + fco[1]*a0[co+1] + fco[2]*a0[co+2]
                     + fco[3]*a1[co] + fco[4]*a1[co+1] + fco[5]*a1[co+2]
                     + fco[6]*a2[co] + fco[7]*a2[co+1] + fco[8]*a2[co+2];
            float e = a1[co + 1] - yt;
            (&od.x)[co] = __expf(-e * e) * (rm * cmv);
        }
        *(float4*)&sdiff[r][c0] = od;
    }
    __syncthreads();

    // ---- phase 3: stream s = wave*4+grp -> output rows [4s, 4s+4),
    //      lane covers cols x4..x4+3; rolling 3-row windows, all b128 ----
    {
        const int y0 = (wave * 4 + grp) * 4;
        float* dst = yout + (size_t)bc * (HH * WW) + (size_t)(h0 + y0) * WW + (w0 + x4);

        float sd0[8], sd1[8], sd2[8];
        float sv0[8], sv1[8], sv2[8];
        float vd0[6], vd1[6], vd2[6];
        *(float4*)&sd0[0] = *(const float4*)&sdiff[y0][x4];
        *(float4*)&sd0[4] = *(const float4*)&sdiff[y0][x4 + 4];
        *(float4*)&sd1[0] = *(const float4*)&sdiff[y0 + 1][x4];
        *(float4*)&sd1[4] = *(const float4*)&sdiff[y0 + 1][x4 + 4];
        *(float4*)&sv0[0] = *(const float4*)&sval[y0 + 1][x4];
        *(float4*)&sv0[4] = *(const float4*)&sval[y0 + 1][x4 + 4];
        *(float4*)&sv1[0] = *(const float4*)&sval[y0 + 2][x4];
        *(float4*)&sv1[4] = *(const float4*)&sval[y0 + 2][x4 + 4];
        #pragma unroll
        for (int j = 0; j < 6; ++j) {
            vd0[j] = sd0[j] * sv0[j + 1];
            vd1[j] = sd1[j] * sv1[j + 1];
        }
        #pragma unroll
        for (int i = 0; i < 4; ++i) {
            const int y = y0 + i;
            *(float4*)&sd2[0] = *(const float4*)&sdiff[y + 2][x4];
            *(float4*)&sd2[4] = *(const float4*)&sdiff[y + 2][x4 + 4];
            *(float4*)&sv2[0] = *(const float4*)&sval[y + 3][x4];
            *(float4*)&sv2[4] = *(const float4*)&sval[y + 3][x4 + 4];
            float dv0[6], dv2[6];
            #pragma unroll
            for (int j = 0; j < 6; ++j) {
                vd2[j] = sd2[j] * sv2[j + 1];
                dv0[j] = vd0[j] - vd1[j];
                dv2[j] = vd2[j] - vd1[j];
            }
            float4 o;
            #pragma unroll
            for (int co = 0; co < 4; ++co) {
                float yt  = fco[0]*sv0[co+1] + fco[1]*sv0[co+2] + fco[2]*sv0[co+3]
                          + fco[3]*sv1[co+1] + fco[4]*sv1[co+2] + fco[5]*sv1[co+3]
                          + fco[6]*sv2[co+1] + fco[7]*sv2[co+2] + fco[8]*sv2[co+3];
                float yd9 = 1e-10f
                          + awk[0]*sd0[co] + awk[1]*sd0[co+1] + awk[2]*sd0[co+2]
                          + awk[3]*sd1[co] + awk[4]*sd1[co+1] + awk[5]*sd1[co+2]
                          + awk[6]*sd2[co] + awk[7]*sd2[co+1] + awk[8]*sd2[co+2];
                float num = wk[0]*dv0[co] + wk[1]*dv0[co+1] + wk[2]*dv0[co+2]
                          + wk[6]*dv2[co] + wk[7]*dv2[co+1] + wk[8]*dv2[co+2];
                (&o.x)[co] = yt - num * __builtin_amdgcn_rcpf(yd9);
            }
            *(float4*)&dst[i * WW] = o;
            #pragma unroll
            for (int j = 0; j < 8; ++j) {
                sd0[j] = sd1[j]; sd1[j] = sd2[j];
                sv0[j] = sv1[j]; sv1[j] = sv2[j];
            }
            #pragma unroll
            for (int j = 0; j < 6; ++j) { vd0[j] = vd1[j]; vd1[j] = vd2[j]; }
        }
    }
}

// ---------------------------------------------------------------------------
extern "C" void kernel_launch(void* const* d_in, const int* in_sizes, int n_in,
                              void* d_out, int out_size, void* d_ws, size_t ws_size,
                              hipStream_t stream) {
    const float* query = (const float*)d_in[0];   // (100,8,64)
    const float* value = (const float*)d_in[1];   // (8,64,256,256)
    // d_in[2..4]: unused scalars
    const float* Wl    = (const float*)d_in[5];   // (18,100)
    const float* bl    = (const float*)d_in[6];   // (18,)
    const float* Wd    = (const float*)d_in[7];   // (100,18)
    const float* bd    = (const float*)d_in[8];   // (100,)

    float* out   = (float*)d_out;
    float* qout  = out;                 // first 100*512 floats
    float* yout  = out + QN * BC;       // then 512*256*256 floats
    float* coef  = (float*)d_ws;        // 512*32 floats = 64 KB

    prep_kernel<<<BC, 128, 0, stream>>>(query, Wl, bl, Wd, bd, qout, coef);

    dim3 grid(WW / 64, HH / 64, BC);
    fused_kernel<<<grid, 256, 0, stream>>>(value, coef, yout);
}

// Round 2
// 279.236 us; speedup vs baseline: 1.1014x; 1.0971x over previous
//
#include <hip/hip_runtime.h>
#include <math.h>

#define HH 256
#define WW 256
#define BC 512   // B*C = 8*64
#define QN 100
#define RBAND 32 // output rows per wave

// ---------------------------------------------------------------------------
// Kernel 1: per-(b,c) 18x100 GEMM + q output + derived conv coefficients.
// coef layout per bc (stride 32 floats): [0..8]=former, [9..17]=wk,
// [18..26]=|wk|, [27..29]=column sums of wk (kept for layout compat).
// ---------------------------------------------------------------------------
__global__ __launch_bounds__(128) void prep_kernel(
    const float* __restrict__ query,   // (100, 8, 64) = (100, 512)
    const float* __restrict__ Wl,      // (18, 100)
    const float* __restrict__ bl,      // (18,)
    const float* __restrict__ Wd,      // (100, 18)
    const float* __restrict__ bd,      // (100,)
    float* __restrict__ qout,          // (100, 512) region of d_out
    float* __restrict__ coef)          // (512, 32) in d_ws
{
    const int bc = blockIdx.x;
    const int t  = threadIdx.x;
    __shared__ float qcol[QN];
    __shared__ float c18[18];

    if (t < QN) qcol[t] = query[t * BC + bc];
    __syncthreads();

    if (t < 18) {
        float acc = bl[t];
        const float* wrow = Wl + t * QN;
        #pragma unroll 4
        for (int qi = 0; qi < QN; ++qi) acc += qcol[qi] * wrow[qi];
        c18[t] = acc;
    }
    __syncthreads();

    if (t < QN) {
        float acc = bd[t];
        const float* wrow = Wd + t * 18;
        #pragma unroll
        for (int k = 0; k < 18; ++k) acc += c18[k] * wrow[k];
        qout[t * BC + bc] = acc;   // q.transpose(2,0,1) layout
    }

    if (t < 18) {
        coef[bc * 32 + t] = c18[t];                      // former / wk
    } else if (t < 27) {
        coef[bc * 32 + t] = fabsf(c18[t - 9]);           // |wk|
    } else if (t < 30) {
        int j = t - 27;
        coef[bc * 32 + t] = c18[9 + j] + c18[12 + j] + c18[15 + j]; // colsum
    }
}

// ---------------------------------------------------------------------------
// Kernel 2: LDS-free streaming stencil. One wave64 spans the full 256-col
// image width (4 cols/lane); each wave streams a 32-row band with rolling
// register windows:
//   v[s][6]: value rows, slot(r) = (r - r0 + 2) & 3, cols [4x-1 .. 4x+4]
//   d[s][6]: diff  rows, slot(r) = (r - r0 + 1) & 3
// Column neighbors via __shfl (image-edge cols are zero = SAME padding).
// Iteration for output row h:  load value(h+2) -> compute diff(h+1) ->
// output(h).  Algebraic fold: res - res_diff =
//   sum_b wk[b]*(vd(h-1)-vd(h)) + wk[6+b]*(vd(h+1)-vd(h)).
// No __syncthreads, no LDS. 4 independent waves per block (4 bands).
// ---------------------------------------------------------------------------
__global__ __launch_bounds__(256, 4) void fused_kernel(
    const float* __restrict__ value,   // (512, 256, 256)
    const float* __restrict__ coef,    // (512, 32)
    float* __restrict__ yout)          // (512, 256, 256) region of d_out
{
    const int bc   = blockIdx.z;
    const int wave = threadIdx.x >> 6;
    const int lane = threadIdx.x & 63;
    const int band = blockIdx.x * 4 + wave;
    const int r0   = band * RBAND;
    const int x4   = lane << 2;

    const bool l0  = (lane == 0);
    const bool l63 = (lane == 63);

    // coefficients: block-uniform address -> scalar loads
    const float* cp = coef + bc * 32;
    float fco[9], awk[9], wk6[6];
    #pragma unroll
    for (int i = 0; i < 9; ++i) { fco[i] = cp[i]; awk[i] = cp[18 + i]; }
    wk6[0] = cp[9];  wk6[1] = cp[10]; wk6[2] = cp[11];
    wk6[3] = cp[15]; wk6[4] = cp[16]; wk6[5] = cp[17];

    const float* vbase = value + (size_t)bc * (HH * WW);
    float*       obase = yout  + (size_t)bc * (HH * WW);

    float v[4][6];
    float d[4][6];

    // load value row r into 6-wide register row (cols 4x-1 .. 4x+4)
    auto LOADV = [&](int r, float* row) {
        if ((unsigned)r < HH) {
            const float4 q = *(const float4*)(vbase + r * WW + x4);
            row[1] = q.x; row[2] = q.y; row[3] = q.z; row[4] = q.w;
            float left  = __shfl_up(q.w, 1);
            float right = __shfl_down(q.x, 1);
            row[0] = l0  ? 0.f : left;   // image col -1 -> 0
            row[5] = l63 ? 0.f : right;  // image col 256 -> 0
        } else {
            #pragma unroll
            for (int m = 0; m < 6; ++m) row[m] = 0.f;
        }
    };

    // diff row r from value rows r-1 (va), r (vb), r+1 (vc)
    auto COMPD = [&](int r, const float* va, const float* vb, const float* vc,
                     float* drow) {
        if ((unsigned)r < HH) {
            float d4[4];
            #pragma unroll
            for (int c = 0; c < 4; ++c) {
                float yt = fco[0]*va[c] + fco[1]*va[c+1] + fco[2]*va[c+2]
                         + fco[3]*vb[c] + fco[4]*vb[c+1] + fco[5]*vb[c+2]
                         + fco[6]*vc[c] + fco[7]*vc[c+1] + fco[8]*vc[c+2];
                float e = vb[c + 1] - yt;
                d4[c] = __expf(-e * e);
            }
            drow[1] = d4[0]; drow[2] = d4[1]; drow[3] = d4[2]; drow[4] = d4[3];
            float left  = __shfl_up(d4[3], 1);
            float right = __shfl_down(d4[0], 1);
            drow[0] = l0  ? 0.f : left;
            drow[5] = l63 ? 0.f : right;
        } else {
            #pragma unroll
            for (int m = 0; m < 6; ++m) drow[m] = 0.f;
        }
    };

    // output row h from value rows h-1..h+1 (vp,vq,vs) and diff rows (dp,dq,ds)
    auto OUTROW = [&](int h, const float* vp, const float* vq, const float* vs,
                      const float* dp, const float* dq, const float* ds) {
        float dv0[6], dv2[6];
        #pragma unroll
        for (int m = 0; m < 6; ++m) {
            float mid = dq[m] * vq[m];
            dv0[m] = dp[m] * vp[m] - mid;
            dv2[m] = ds[m] * vs[m] - mid;
        }
        float4 o;
        #pragma unroll
        for (int c = 0; c < 4; ++c) {
            float yt  = fco[0]*vp[c] + fco[1]*vp[c+1] + fco[2]*vp[c+2]
                      + fco[3]*vq[c] + fco[4]*vq[c+1] + fco[5]*vq[c+2]
                      + fco[6]*vs[c] + fco[7]*vs[c+1] + fco[8]*vs[c+2];
            float yd9 = 1e-10f
                      + awk[0]*dp[c] + awk[1]*dp[c+1] + awk[2]*dp[c+2]
                      + awk[3]*dq[c] + awk[4]*dq[c+1] + awk[5]*dq[c+2]
                      + awk[6]*ds[c] + awk[7]*ds[c+1] + awk[8]*ds[c+2];
            float num = wk6[0]*dv0[c] + wk6[1]*dv0[c+1] + wk6[2]*dv0[c+2]
                      + wk6[3]*dv2[c] + wk6[4]*dv2[c+1] + wk6[5]*dv2[c+2];
            (&o.x)[c] = yt - num * __builtin_amdgcn_rcpf(yd9);
        }
        *(float4*)(obase + h * WW + x4) = o;
    };

    // ---- prologue: value rows r0-2 .. r0+1, diff rows r0-1, r0 ----
    LOADV(r0 - 2, v[0]);
    LOADV(r0 - 1, v[1]);
    LOADV(r0,     v[2]);
    LOADV(r0 + 1, v[3]);
    COMPD(r0 - 1, v[0], v[1], v[2], d[0]);
    COMPD(r0,     v[1], v[2], v[3], d[1]);

    // ---- main loop: 32 rows, unrolled x4 so all slot indices are static ----
    for (int io = 0; io < RBAND; io += 4) {
        #pragma unroll
        for (int j = 0; j < 4; ++j) {
            const int h = r0 + io + j;
            // v slot(r) = (r - r0 + 2) & 3; io % 4 == 0 so reduce mod j only
            LOADV(h + 2, v[j & 3]);                         // drops row h-2
            COMPD(h + 1, v[(j + 2) & 3], v[(j + 3) & 3], v[j & 3],
                  d[(j + 2) & 3]);                          // drops diff h-3
            OUTROW(h, v[(j + 1) & 3], v[(j + 2) & 3], v[(j + 3) & 3],
                   d[j & 3], d[(j + 1) & 3], d[(j + 2) & 3]);
        }
    }
}

// ---------------------------------------------------------------------------
extern "C" void kernel_launch(void* const* d_in, const int* in_sizes, int n_in,
                              void* d_out, int out_size, void* d_ws, size_t ws_size,
                              hipStream_t stream) {
    const float* query = (const float*)d_in[0];   // (100,8,64)
    const float* value = (const float*)d_in[1];   // (8,64,256,256)
    // d_in[2..4]: unused scalars
    const float* Wl    = (const float*)d_in[5];   // (18,100)
    const float* bl    = (const float*)d_in[6];   // (18,)
    const float* Wd    = (const float*)d_in[7];   // (100,18)
    const float* bd    = (const float*)d_in[8];   // (100,)

    float* out   = (float*)d_out;
    float* qout  = out;                 // first 100*512 floats
    float* yout  = out + QN * BC;       // then 512*256*256 floats
    float* coef  = (float*)d_ws;        // 512*32 floats = 64 KB

    prep_kernel<<<BC, 128, 0, stream>>>(query, Wl, bl, Wd, bd, qout, coef);

    // 8 bands of 32 rows per image; 4 waves (bands) per block
    dim3 grid(HH / (RBAND * 4), 1, BC);
    fused_kernel<<<grid, 256, 0, stream>>>(value, coef, yout);
}